// Round 4
// baseline (536.067 us; speedup 1.0000x reference)
//
#include <hip/hip_runtime.h>
#include <hip/hip_bf16.h>
#include <stdint.h>

typedef __bf16 bf16_t;
typedef bf16_t bf16x8 __attribute__((ext_vector_type(8)));
typedef bf16_t bf16x2 __attribute__((ext_vector_type(2)));
typedef float  f32x4  __attribute__((ext_vector_type(4)));
typedef float  f32x2  __attribute__((ext_vector_type(2)));

#define N_FEAT 128

// ---- detect edge integer width: int64 edges have zero high words ----
// (values < 1e5 << 2^31; 32 random int32 edge values all-zero: p ~ 1e-160)
__global__ void detect_k(const int* __restrict__ edges, int* __restrict__ flag) {
    int s = 0;
    for (int i = 1; i < 64; i += 2) s |= edges[i];
    *flag = (s == 0) ? 1 : 0;   // 1 => int64 storage (stride 2), 0 => int32
}
// read logical element i of the edge buffer under detected width
__device__ inline int eread(const int* __restrict__ edges, int f, long i) {
    return f ? edges[2 * i] : edges[i];
}

__device__ inline bf16x8 cvt8(const float* __restrict__ p) {
    f32x4 lo = *(const f32x4*)p;
    f32x4 hi = *(const f32x4*)(p + 4);
    bf16x8 r;
    r[0] = (bf16_t)lo[0]; r[1] = (bf16_t)lo[1]; r[2] = (bf16_t)lo[2]; r[3] = (bf16_t)lo[3];
    r[4] = (bf16_t)hi[0]; r[5] = (bf16_t)hi[1]; r[6] = (bf16_t)hi[2]; r[7] = (bf16_t)hi[3];
    return r;
}

// ---- X_hat = X @ W^T : fp32 in -> bf16 frags -> MFMA fp32 acc -> bf16 out --
// One wave per 16 rows; W (64KB fp32) is L2-resident, X rows read once.
//   A: lane holds A[row=lane&15][k=(lane>>4)*8+i]
//   B: lane holds B[k=(lane>>4)*8+i][col=lane&15] == W[col][k] (K-contig)
//   D: col=lane&15, row=(lane>>4)*4+reg   [m89/m91]
__global__ __launch_bounds__(64) void gemm_xwt(const float* __restrict__ X,
                                               const float* __restrict__ W,
                                               bf16_t* __restrict__ Xhat) {
    const int lane = threadIdx.x;
    const int m  = lane & 15;
    const int kq = lane >> 4;
    const long r0 = (long)blockIdx.x * 16;

    f32x4 acc[8];
#pragma unroll
    for (int c = 0; c < 8; ++c) acc[c] = (f32x4){0.f, 0.f, 0.f, 0.f};

    const float* xrow = X + (r0 + m) * N_FEAT + kq * 8;
#pragma unroll
    for (int kb = 0; kb < 4; ++kb) {
        bf16x8 a = cvt8(xrow + kb * 32);
#pragma unroll
        for (int c = 0; c < 8; ++c) {
            bf16x8 b = cvt8(W + (c * 16 + m) * N_FEAT + kb * 32 + kq * 8);
            acc[c] = __builtin_amdgcn_mfma_f32_16x16x32_bf16(a, b, acc[c], 0, 0, 0);
        }
    }
#pragma unroll
    for (int c = 0; c < 8; ++c) {
#pragma unroll
        for (int i = 0; i < 4; ++i) {
            long r = r0 + kq * 4 + i;
            Xhat[r * N_FEAT + c * 16 + m] = (bf16_t)acc[c][i];
        }
    }
}

// ---- degrees: cnt_row (CSR sizes), cnt_col (normalization) ----
__global__ void degree_k(const int* __restrict__ edges, const int* __restrict__ flag,
                         int E, int N,
                         int* __restrict__ cnt_row, int* __restrict__ cnt_col) {
    int e = blockIdx.x * blockDim.x + threadIdx.x;
    int f = *flag;
    if (e < E) {
        int r = eread(edges, f, e);
        int c = eread(edges, f, (long)E + e);
        if ((unsigned)r < (unsigned)N) atomicAdd(&cnt_row[r], 1);
        if ((unsigned)c < (unsigned)N) atomicAdd(&cnt_col[c], 1);
    }
}

__global__ void degree_col_k(const int* __restrict__ edges, const int* __restrict__ flag,
                             int E, int N, int* __restrict__ cnt_col) {
    int e = blockIdx.x * blockDim.x + threadIdx.x;
    int f = *flag;
    if (e < E) {
        int c = eread(edges, f, (long)E + e);
        if ((unsigned)c < (unsigned)N) atomicAdd(&cnt_col[c], 1);
    }
}

// ============ Plan A: order-free CSR (by ROW degree) + gather ============

// cur[n] = segment offset (order-free); overwrite cnt_col in place with
// dinv = rsqrt(col_degree + 1). (no __restrict__ on the aliased pair)
__global__ void alloc_k(const int* __restrict__ cnt_row, int N,
                        int* __restrict__ cur, int* __restrict__ total,
                        int* cnt_col_in, float* dinv_out) {
    int n = blockIdx.x * blockDim.x + threadIdx.x;
    if (n < N) {
        cur[n] = atomicAdd(total, cnt_row[n]);
        int dc = cnt_col_in[n];
        dinv_out[n] = rsqrtf((float)(dc + 1));
    }
}

__global__ void scatter_k(const int* __restrict__ edges, const int* __restrict__ flag,
                          int E, int N, int* __restrict__ cur, int* __restrict__ ecol) {
    int e = blockIdx.x * blockDim.x + threadIdx.x;
    int f = *flag;
    if (e < E) {
        int r = eread(edges, f, e);
        if ((unsigned)r < (unsigned)N) {
            int p = atomicAdd(&cur[r], 1);
            if ((unsigned)p < (unsigned)E)          // guard: clean fail, not fault
                ecol[p] = eread(edges, f, (long)E + e);
        }
    }
}

// one wave per node; lane j owns features 2j,2j+1. ecol/cnt/dinv reads are
// wave-uniform (scalar); Xhat row read is one coalesced 256B burst.
__global__ __launch_bounds__(64) void gather_k(const int* __restrict__ ecol,
                                               const int* __restrict__ cur,
                                               const int* __restrict__ cnt_row,
                                               const float* __restrict__ dinv,
                                               const bf16_t* __restrict__ Xhat,
                                               int N,
                                               float* __restrict__ out) {
    const int n = blockIdx.x;
    const int j = threadIdx.x;
    const int c = cnt_row[n];
    const int s = cur[n] - c;          // cur ended at start+cnt_row after scatter
    const float dn = dinv[n];

    bf16x2 xs = *(const bf16x2*)(Xhat + (long)n * N_FEAT + 2 * j);
    float a0 = dn * (float)xs[0];      // self-loop (outer dn applied at end)
    float a1 = dn * (float)xs[1];

    for (int e = 0; e < c; ++e) {
        int cc = ecol[s + e];
        if ((unsigned)cc >= (unsigned)N) continue;   // guard
        float dc = dinv[cc];
        bf16x2 xv = *(const bf16x2*)(Xhat + (long)cc * N_FEAT + 2 * j);
        a0 += dc * (float)xv[0];
        a1 += dc * (float)xv[1];
    }
    f32x2 o; o[0] = dn * a0; o[1] = dn * a1;
    *(f32x2*)(out + (long)n * N_FEAT + 2 * j) = o;
}

// ============ Plan B (small ws): fp32 atomicAdd into d_out ============

__global__ __launch_bounds__(128) void self_k(const int* __restrict__ cnt_col,
                                              const bf16_t* __restrict__ Xhat,
                                              float* __restrict__ out) {
    const int n = blockIdx.x;
    const int j = threadIdx.x;
    const float dn2 = 1.0f / (float)(cnt_col[n] + 1);
    out[(long)n * N_FEAT + j] = dn2 * (float)Xhat[(long)n * N_FEAT + j];
}

__global__ __launch_bounds__(128) void edge_add_k(const int* __restrict__ edges,
                                                  const int* __restrict__ flag,
                                                  int E, int N,
                                                  const int* __restrict__ cnt_col,
                                                  const bf16_t* __restrict__ Xhat,
                                                  float* __restrict__ out) {
    const int e = blockIdx.x;
    const int j = threadIdx.x;
    int f = *flag;
    const int r = eread(edges, f, e);
    const int c = eread(edges, f, (long)E + e);
    if ((unsigned)r >= (unsigned)N || (unsigned)c >= (unsigned)N) return;
    const float val = rsqrtf((float)(cnt_col[r] + 1)) * rsqrtf((float)(cnt_col[c] + 1));
    atomicAdd(&out[(long)r * N_FEAT + j], val * (float)Xhat[(long)c * N_FEAT + j]);
}

extern "C" void kernel_launch(void* const* d_in, const int* in_sizes, int n_in,
                              void* d_out, int out_size, void* d_ws, size_t ws_size,
                              hipStream_t stream) {
    const float* X = (const float*)d_in[0];
    const float* W = (const float*)d_in[1];
    const int* edges = (const int*)d_in[2];
    const int E = in_sizes[2] / 2;          // 1,600,000 (element count / 2)
    const int N = in_sizes[0] / N_FEAT;     // 100,000

    char* ws = (char*)d_ws;
    // layout: flag(16) | Xhat bf16 | cnt_col(->dinv) | [cnt_row | cur | total | ecol]
    int*    flag = (int*)ws;
    bf16_t* Xhat = (bf16_t*)(ws + 16);
    const size_t xhat_b = (size_t)N * N_FEAT * sizeof(bf16_t);   // 25,600,000
    const size_t n4     = (size_t)N * 4;
    int* cnt_col = (int*)(ws + 16 + xhat_b);

    const size_t need_A = 16 + xhat_b + n4 * 3 + 16 + (size_t)E * 4; // 33,200,032
    const size_t need_B = 16 + xhat_b + n4;                          // 26,000,016

    if (ws_size >= need_A) {
        int*   cnt_row = (int*)(ws + 16 + xhat_b + n4);
        int*   cur     = (int*)(ws + 16 + xhat_b + n4 * 2);
        int*   total   = (int*)(ws + 16 + xhat_b + n4 * 3);
        int*   ecol    = (int*)(ws + 16 + xhat_b + n4 * 3 + 16);
        float* dinv    = (float*)cnt_col;     // overwritten in alloc_k

        hipMemsetAsync(cnt_col, 0, n4 * 2, stream);   // cnt_col + cnt_row
        hipMemsetAsync(total, 0, 16, stream);
        detect_k<<<1, 1, 0, stream>>>(edges, flag);
        gemm_xwt<<<N / 16, 64, 0, stream>>>(X, W, Xhat);
        degree_k<<<(E + 255) / 256, 256, 0, stream>>>(edges, flag, E, N, cnt_row, cnt_col);
        alloc_k<<<(N + 255) / 256, 256, 0, stream>>>(cnt_row, N, cur, total, cnt_col, dinv);
        scatter_k<<<(E + 255) / 256, 256, 0, stream>>>(edges, flag, E, N, cur, ecol);
        gather_k<<<N, 64, 0, stream>>>(ecol, cur, cnt_row, dinv, Xhat, N, (float*)d_out);
    } else if (ws_size >= need_B) {
        hipMemsetAsync(cnt_col, 0, n4, stream);
        detect_k<<<1, 1, 0, stream>>>(edges, flag);
        gemm_xwt<<<N / 16, 64, 0, stream>>>(X, W, Xhat);
        degree_col_k<<<(E + 255) / 256, 256, 0, stream>>>(edges, flag, E, N, cnt_col);
        self_k<<<N, 128, 0, stream>>>(cnt_col, Xhat, (float*)d_out);
        edge_add_k<<<E, 128, 0, stream>>>(edges, flag, E, N, cnt_col, Xhat, (float*)d_out);
    }
    // else: ws too small for any plan — launch nothing (clean absmax
    // diagnostic instead of a fault).
}